// Round 7
// baseline (442.418 us; speedup 1.0000x reference)
//
#include <hip/hip_runtime.h>

#define D_IN   1024
#define D_OUTD 8192
#define ORDER  3
#define NCOL   2048

// Persistent device-side tables (rewritten every kernel_launch call).
__device__ float2 g_tw[D_OUTD / 2];      // W_8192^k, k in [0,4096)
__device__ int    g_h[ORDER * D_IN];
__device__ float  g_w[ORDER * D_IN];

__global__ void tw_kernel() {
    int k = blockIdx.x * 256 + threadIdx.x;
    if (k < D_OUTD / 2) {
        double ang = -2.0 * 3.14159265358979323846 * (double)k / (double)D_OUTD;
        g_tw[k] = make_float2((float)cos(ang), (float)sin(ang));
    }
}

__global__ void extract_kernel(const float* __restrict__ hmaps) {
    int idx = blockIdx.x * 256 + threadIdx.x;
    if (idx >= ORDER * D_OUTD * D_IN) return;
    float v = hmaps[idx];
    if (v != 0.0f) {
        int i   = idx % D_IN;
        int rem = idx / D_IN;
        int d   = rem % D_OUTD;
        int o   = rem / D_OUTD;
        g_h[o * D_IN + i] = d;
        g_w[o * D_IN + i] = v;
    }
}

// x [D_IN][N] -> xT [N][D_IN] so sketch blocks read a contiguous 4KB column.
__global__ void xt_kernel(const float* __restrict__ in, float* __restrict__ out) {
    __shared__ float tile[32][33];
    int i0 = blockIdx.x * 32;
    int n0 = blockIdx.y * 32;
    int tx = threadIdx.x;
    int ty = threadIdx.y;
#pragma unroll
    for (int j = 0; j < 32; j += 8)
        tile[ty + j][tx] = in[(i0 + ty + j) * NCOL + n0 + tx];
    __syncthreads();
#pragma unroll
    for (int j = 0; j < 32; j += 8)
        out[(n0 + ty + j) * D_IN + i0 + tx] = tile[tx][ty + j];
}

__device__ __forceinline__ float2 cmul(float2 a, float2 b) {
    return make_float2(a.x * b.x - a.y * b.y, a.x * b.y + a.y * b.x);
}
__device__ __forceinline__ float2 csqr(float2 a) {
    return make_float2(a.x * a.x - a.y * a.y, 2.0f * a.x * a.y);
}
// compile-time 16th roots of unity: e^{-2*pi*i*k/16}, k=0..7
__device__ __forceinline__ float2 c16(int k) {
    constexpr float R[8] = { 1.0f,  0.92387953251128674f,  0.70710678118654757f,  0.38268343236508978f,
                             0.0f, -0.38268343236508978f, -0.70710678118654757f, -0.92387953251128674f };
    constexpr float I[8] = { 0.0f, -0.38268343236508978f, -0.70710678118654757f, -0.92387953251128674f,
                            -1.0f, -0.92387953251128674f, -0.70710678118654757f, -0.38268343236508978f };
    return make_float2(R[k], I[k]);
}

// 4 DIF stages along the register dimension; base twiddle BASE, squared per stage.
#define REG_PHASE_FWD(XR, XI, BASE)                                              \
    {                                                                            \
        float2 ba_ = (BASE);                                                     \
        _Pragma("unroll")                                                        \
        for (int m = 3; m >= 0; --m) {                                           \
            const int half = 1 << m;                                             \
            float2 tw[8];                                                        \
            _Pragma("unroll")                                                    \
            for (int lo = 0; lo < half; ++lo) tw[lo] = cmul(ba_, c16(lo << (3 - m))); \
            _Pragma("unroll")                                                    \
            for (int p = 0; p < 8; ++p) {                                        \
                const int lo = p & (half - 1);                                   \
                const int hi = p >> m;                                           \
                const int j0 = (hi << (m + 1)) + lo;                             \
                const int j1 = j0 + half;                                        \
                const float2 w = tw[lo];                                         \
                float ar = XR[j0], ai = XI[j0];                                  \
                float br = XR[j1], bi = XI[j1];                                  \
                XR[j0] = ar + br; XI[j0] = ai + bi;                              \
                float dr = ar - br, di = ai - bi;                                \
                XR[j1] = dr * w.x - di * w.y;                                    \
                XI[j1] = dr * w.y + di * w.x;                                    \
            }                                                                    \
            if (m) ba_ = csqr(ba_);                                              \
        }                                                                        \
    }

// 4 inverse DIT stages along register dimension; conj twiddles applied inline.
#define REG_PHASE_INV(XR, XI, B8, B4, B2, B1)                                    \
    {                                                                            \
        const float2 bas_[4] = { (B8), (B4), (B2), (B1) };                       \
        _Pragma("unroll")                                                        \
        for (int m = 0; m <= 3; ++m) {                                           \
            const int half = 1 << m;                                             \
            float2 tw[8];                                                        \
            _Pragma("unroll")                                                    \
            for (int lo = 0; lo < half; ++lo) tw[lo] = cmul(bas_[m], c16(lo << (3 - m))); \
            _Pragma("unroll")                                                    \
            for (int p = 0; p < 8; ++p) {                                        \
                const int lo = p & (half - 1);                                   \
                const int hi = p >> m;                                           \
                const int j0 = (hi << (m + 1)) + lo;                             \
                const int j1 = j0 + half;                                        \
                const float2 w = tw[lo];                                         \
                float tr = XR[j1] * w.x + XI[j1] * w.y;                          \
                float ti = XI[j1] * w.x - XR[j1] * w.y;                          \
                XR[j1] = XR[j0] - tr; XI[j1] = XI[j0] - ti;                      \
                XR[j0] += tr; XI[j0] += ti;                                      \
            }                                                                    \
        }                                                                        \
    }

// Forward core: counts in buf (phi-addressed) -> 12 of 13 DIF stages done,
// post-C' values left in XR/XI (slot 32*(t>>1)+2j+e) AND staged in buf for the
// pair-unpack (final stride-1 stage is folded into the unpack read).
#define FWD_CORE(XR, XI)                                                         \
    _Pragma("unroll")                                                            \
    for (int j = 0; j < 16; ++j) { float2 v_ = buf[tA + 512 * j]; XR[j] = v_.x; XI[j] = v_.y; } \
    REG_PHASE_FWD(XR, XI, wt)                                                    \
    _Pragma("unroll")                                                            \
    for (int j = 0; j < 16; ++j) buf[tA + 512 * j] = make_float2(XR[j], XI[j]);  \
    __syncthreads();                                                             \
    _Pragma("unroll")                                                            \
    for (int j = 0; j < 16; ++j) { float2 v_ = buf[bB + 32 * j + (s ^ (j << 1))]; XR[j] = v_.x; XI[j] = v_.y; } \
    REG_PHASE_FWD(XR, XI, bb16)                                                  \
    _Pragma("unroll")                                                            \
    for (int j = 0; j < 16; ++j) buf[bB + 32 * j + (s ^ (j << 1))] = make_float2(XR[j], XI[j]); \
    __syncthreads();                                                             \
    _Pragma("unroll")                                                            \
    for (int j = 0; j < 16; ++j) { float2 v_ = buf[pc + 2 * (j ^ kc)]; XR[j] = v_.x; XI[j] = v_.y; } \
    REG_PHASE_FWD(XR, XI, bc)                                                    \
    _Pragma("unroll")                                                            \
    for (int j = 0; j < 16; ++j) buf[pc + 2 * (j ^ kc)] = make_float2(XR[j], XI[j]); \
    __syncthreads();

// Round-7: 13 stages = 4(reg) + ex + 4(reg) + ex + 4(reg) + [stride-1 folded
// into the Hermitian-unpack LDS pass]. Forward bodies have ZERO shfl; all LDS
// traffic is b64/b128 through involution phi(q) = q ^ (((q>>5)&15)<<1)
// (conflict-free for every access pattern; exchange writes hit just-read
// per-thread slots so no extra barriers). Two columns per block as in round 6.
__launch_bounds__(512, 2)
__global__ void sketch_kernel(const float* __restrict__ x, float* __restrict__ outbuf,
                              int staged, int xcoal) {
    __shared__ __align__(16) float2 buf[D_OUTD];
    const int n0 = 2 * blockIdx.x;
    const int n1 = n0 + 1;
    const int t = threadIdx.x;
    const int e = t & 1;
    const int s = t & 31;
    const int kA = ((t >> 5) & 15) << 1;
    const int tA = t ^ kA;                 // phi(t + 512j) = tA + 512j
    const int bB = 512 * (t >> 5);         // phi(B slot)   = bB + 32j + (s ^ 2j)
    const int kc = (t >> 1) & 15;
    const int pp = 32 * (t >> 1);          // own pair base (swizzled: pp + 2*(j^kc))
    const int pc = pp + e;                 // phi(C slot)   = pc + 2*(j^kc)
    const int qc0 = pp + e;                // TRUE C slot   = qc0 + 2j
    const float sgE = e ? -1.0f : 1.0f;

    float xA0, xA1, xB0, xB1;
    if (xcoal) {
        xA0 = x[n0 * D_IN + t]; xA1 = x[n0 * D_IN + t + 512];
        xB0 = x[n1 * D_IN + t]; xB1 = x[n1 * D_IN + t + 512];
    } else {
        xA0 = x[t * NCOL + n0]; xA1 = x[(t + 512) * NCOL + n0];
        xB0 = x[t * NCOL + n1]; xB1 = x[(t + 512) * NCOL + n1];
    }

    // twiddle seeds: wt = W^t (phase A), bb16 = W^(16s) (phase B),
    // bc = W_32^e (phase C'), all other twiddles from squaring chains + c16.
    const float2 wt   = g_tw[t];
    const float2 ws   = g_tw[s];
    const float2 bb16 = csqr(csqr(csqr(csqr(ws))));
    const float2 bc   = e ? make_float2(0.98078528040323044f, -0.19509032201612825f)
                          : make_float2(1.0f, 0.0f);

    float P0r[16], P0i[16], P1r[16], P1i[16];

    // ================= body A: Z = c2[n0] + i*c2[n1] -> split F2 =================
    {
        float Ar[16], Ai[16];
#pragma unroll
        for (int j = 0; j < 16; ++j) buf[tA + 512 * j] = make_float2(0.0f, 0.0f);
        __syncthreads();
        {
            const int   h0 = g_h[2 * D_IN + t];
            const float w0 = g_w[2 * D_IN + t];
            const int   h1 = g_h[2 * D_IN + t + 512];
            const float w1 = g_w[2 * D_IN + t + 512];
            const int   p0 = h0 ^ (((h0 >> 5) & 15) << 1);
            const int   p1 = h1 ^ (((h1 >> 5) & 15) << 1);
            atomicAdd(&buf[p0].x, w0 * xA0);
            atomicAdd(&buf[p0].y, w0 * xB0);
            atomicAdd(&buf[p1].x, w1 * xA1);
            atomicAdd(&buf[p1].y, w1 * xB1);
        }
        __syncthreads();

        FWD_CORE(Ar, Ai)

#pragma unroll
        for (int j = 0; j < 16; ++j) {
            const int q = qc0 + 2 * j;
            const float4 ov = *reinterpret_cast<const float4*>(&buf[pp + 2 * (j ^ kc)]);
            const int L   = 31 - __clz(q | 1);
            const int pb  = (q ^ ((1 << L) - 1)) & ~1;
            const int pph = pb ^ (((pb >> 5) & 15) << 1);
            const float4 pv = *reinterpret_cast<const float4*>(&buf[pph]);
            const float sgP = (q < 2) ? sgE : -sgE;
            const float ar  = ov.x + sgE * ov.z;       // Z[q]
            const float ai  = ov.y + sgE * ov.w;
            const float pbr =  (pv.x + sgP * pv.z);    // conj(Z[sigma(q)])
            const float pbi = -(pv.y + sgP * pv.w);
            P0r[j] =  0.5f * (ar + pbr);
            P0i[j] =  0.5f * (ai + pbi);
            P1r[j] =  0.5f * (ai - pbi);
            P1i[j] = -0.5f * (ar - pbr);
        }
        __syncthreads();
    }

    // ================= body B: Z = c0[n0] + i*c1[n0]; P0 *= G =================
    {
        float Ar[16], Ai[16];
#pragma unroll
        for (int j = 0; j < 16; ++j) buf[tA + 512 * j] = make_float2(0.0f, 0.0f);
        __syncthreads();
        {
            const int   h0 = g_h[t];            const float w0 = g_w[t];
            const int   h1 = g_h[t + 512];      const float w1 = g_w[t + 512];
            const int   h2 = g_h[D_IN + t];     const float w2 = g_w[D_IN + t];
            const int   h3 = g_h[D_IN + t + 512]; const float w3 = g_w[D_IN + t + 512];
            const int   p0 = h0 ^ (((h0 >> 5) & 15) << 1);
            const int   p1 = h1 ^ (((h1 >> 5) & 15) << 1);
            const int   p2 = h2 ^ (((h2 >> 5) & 15) << 1);
            const int   p3 = h3 ^ (((h3 >> 5) & 15) << 1);
            atomicAdd(&buf[p0].x, w0 * xA0);
            atomicAdd(&buf[p1].x, w1 * xA1);
            atomicAdd(&buf[p2].y, w2 * xA0);
            atomicAdd(&buf[p3].y, w3 * xA1);
        }
        __syncthreads();

        FWD_CORE(Ar, Ai)

#pragma unroll
        for (int j = 0; j < 16; ++j) {
            const int q = qc0 + 2 * j;
            const float4 ov = *reinterpret_cast<const float4*>(&buf[pp + 2 * (j ^ kc)]);
            const int L   = 31 - __clz(q | 1);
            const int pb  = (q ^ ((1 << L) - 1)) & ~1;
            const int pph = pb ^ (((pb >> 5) & 15) << 1);
            const float4 pv = *reinterpret_cast<const float4*>(&buf[pph]);
            const float sgP = (q < 2) ? sgE : -sgE;
            const float ar  = ov.x + sgE * ov.z;
            const float ai  = ov.y + sgE * ov.w;
            const float pbr =  (pv.x + sgP * pv.z);
            const float pbi = -(pv.y + sgP * pv.w);
            const float a2r = ar * ar - ai * ai;
            const float a2i = 2.0f * ar * ai;
            const float b2r = pbr * pbr - pbi * pbi;
            const float b2i = 2.0f * pbr * pbi;
            const float gr =  0.25f * (a2i - b2i);     // G = -i*(A^2 - B^2)/4
            const float gi = -0.25f * (a2r - b2r);
            const float fr = P0r[j], fi = P0i[j];
            P0r[j] = gr * fr - gi * fi;
            P0i[j] = gr * fi + gi * fr;
        }
        __syncthreads();
    }

    // ================= body C: Z = c0[n1] + i*c1[n1]; P1 *= G =================
    {
        float Ar[16], Ai[16];
#pragma unroll
        for (int j = 0; j < 16; ++j) buf[tA + 512 * j] = make_float2(0.0f, 0.0f);
        __syncthreads();
        {
            const int   h0 = g_h[t];            const float w0 = g_w[t];
            const int   h1 = g_h[t + 512];      const float w1 = g_w[t + 512];
            const int   h2 = g_h[D_IN + t];     const float w2 = g_w[D_IN + t];
            const int   h3 = g_h[D_IN + t + 512]; const float w3 = g_w[D_IN + t + 512];
            const int   p0 = h0 ^ (((h0 >> 5) & 15) << 1);
            const int   p1 = h1 ^ (((h1 >> 5) & 15) << 1);
            const int   p2 = h2 ^ (((h2 >> 5) & 15) << 1);
            const int   p3 = h3 ^ (((h3 >> 5) & 15) << 1);
            atomicAdd(&buf[p0].x, w0 * xB0);
            atomicAdd(&buf[p1].x, w1 * xB1);
            atomicAdd(&buf[p2].y, w2 * xB0);
            atomicAdd(&buf[p3].y, w3 * xB1);
        }
        __syncthreads();

        FWD_CORE(Ar, Ai)

#pragma unroll
        for (int j = 0; j < 16; ++j) {
            const int q = qc0 + 2 * j;
            const float4 ov = *reinterpret_cast<const float4*>(&buf[pp + 2 * (j ^ kc)]);
            const int L   = 31 - __clz(q | 1);
            const int pb  = (q ^ ((1 << L) - 1)) & ~1;
            const int pph = pb ^ (((pb >> 5) & 15) << 1);
            const float4 pv = *reinterpret_cast<const float4*>(&buf[pph]);
            const float sgP = (q < 2) ? sgE : -sgE;
            const float ar  = ov.x + sgE * ov.z;
            const float ai  = ov.y + sgE * ov.w;
            const float pbr =  (pv.x + sgP * pv.z);
            const float pbi = -(pv.y + sgP * pv.w);
            const float a2r = ar * ar - ai * ai;
            const float a2i = 2.0f * ar * ai;
            const float b2r = pbr * pbr - pbi * pbi;
            const float b2i = 2.0f * pbr * pbi;
            const float gr =  0.25f * (a2i - b2i);
            const float gi = -0.25f * (a2r - b2r);
            const float fr = P1r[j], fi = P1i[j];
            P1r[j] = gr * fr - gi * fi;
            P1i[j] = gr * fi + gi * fr;
        }
        __syncthreads();
    }

    // ================= inverse: Q = P0 + i*P1, one IFFT for both columns =====
    float Qr[16], Qi[16];
#pragma unroll
    for (int j = 0; j < 16; ++j) {
        Qr[j] = P0r[j] - P1i[j];
        Qi[j] = P0i[j] + P1r[j];
    }

    // stride-1 inverse stage (twiddle-free): pairs are lanes (t, t^1)
#pragma unroll
    for (int j = 0; j < 16; ++j) {
        const float orr = __shfl_xor(Qr[j], 1, 64);
        const float oii = __shfl_xor(Qi[j], 1, 64);
        Qr[j] = orr + sgE * Qr[j];
        Qi[j] = oii + sgE * Qi[j];
    }

    // C'-inv: strides 2..16
    {
        const float2 bc2 = csqr(bc), bc4 = csqr(bc2), bc8 = csqr(bc4);
        REG_PHASE_INV(Qr, Qi, bc8, bc4, bc2, bc)
    }

    // ex2-inv: C layout -> B layout
#pragma unroll
    for (int j = 0; j < 16; ++j) buf[pc + 2 * (j ^ kc)] = make_float2(Qr[j], Qi[j]);
    __syncthreads();
#pragma unroll
    for (int j = 0; j < 16; ++j) { float2 v_ = buf[bB + 32 * j + (s ^ (j << 1))]; Qr[j] = v_.x; Qi[j] = v_.y; }

    // B-inv: strides 32..256
    {
        const float2 bb32 = csqr(bb16), bb64 = csqr(bb32), bb128 = csqr(bb64);
        REG_PHASE_INV(Qr, Qi, bb128, bb64, bb32, bb16)
    }

    // ex1-inv: B layout -> A layout (writes hit just-read slots, no bar needed)
#pragma unroll
    for (int j = 0; j < 16; ++j) buf[bB + 32 * j + (s ^ (j << 1))] = make_float2(Qr[j], Qi[j]);
    __syncthreads();
#pragma unroll
    for (int j = 0; j < 16; ++j) { float2 v_ = buf[tA + 512 * j]; Qr[j] = v_.x; Qi[j] = v_.y; }

    // A-inv: strides 512..4096
    {
        const float2 wa2 = csqr(wt), wa4 = csqr(wa2), wa8 = csqr(wa4);
        REG_PHASE_INV(Qr, Qi, wa8, wa4, wa2, wt)
    }

    const float scale = 1.0f / (float)D_OUTD;
    if (staged) {
#pragma unroll
        for (int j = 0; j < 16; ++j) {
            outbuf[n0 * D_OUTD + t + 512 * j] = Qr[j] * scale;   // Re -> column n0
            outbuf[n1 * D_OUTD + t + 512 * j] = Qi[j] * scale;   // Im -> column n1
        }
    } else {
#pragma unroll
        for (int j = 0; j < 16; ++j) {
            outbuf[(t + 512 * j) * NCOL + n0] = Qr[j] * scale;
            outbuf[(t + 512 * j) * NCOL + n1] = Qi[j] * scale;
        }
    }
}

// [N][D_out] -> [D_out][N], 32x32 tiles
__global__ void transpose_kernel(const float* __restrict__ in, float* __restrict__ out) {
    __shared__ float tile[32][33];
    int d0 = blockIdx.x * 32;
    int n0 = blockIdx.y * 32;
    int tx = threadIdx.x;
    int ty = threadIdx.y;
#pragma unroll
    for (int j = 0; j < 32; j += 8)
        tile[ty + j][tx] = in[(n0 + ty + j) * D_OUTD + d0 + tx];
    __syncthreads();
#pragma unroll
    for (int j = 0; j < 32; j += 8)
        out[(d0 + ty + j) * NCOL + n0 + tx] = tile[tx][ty + j];
}

extern "C" void kernel_launch(void* const* d_in, const int* in_sizes, int n_in,
                              void* d_out, int out_size, void* d_ws, size_t ws_size,
                              hipStream_t stream) {
    (void)in_sizes; (void)n_in; (void)out_size;
    const float* x     = (const float*)d_in[0];
    const float* hmaps = (const float*)d_in[1];
    float* out = (float*)d_out;

    tw_kernel<<<(D_OUTD / 2 + 255) / 256, 256, 0, stream>>>();
    extract_kernel<<<(ORDER * D_OUTD * D_IN + 255) / 256, 256, 0, stream>>>(hmaps);

    const size_t stage_bytes = (size_t)NCOL * D_OUTD * sizeof(float);
    const size_t xt_bytes    = (size_t)NCOL * D_IN * sizeof(float);

    const float* xs = x;
    int xcoal = 0;
    if (ws_size >= stage_bytes + xt_bytes) {
        float* xT = (float*)((char*)d_ws + stage_bytes);
        xt_kernel<<<dim3(D_IN / 32, NCOL / 32), dim3(32, 8), 0, stream>>>(x, xT);
        xs = xT;
        xcoal = 1;
    }

    if (ws_size >= stage_bytes) {
        float* stag = (float*)d_ws;
        sketch_kernel<<<NCOL / 2, 512, 0, stream>>>(xs, stag, 1, xcoal);
        transpose_kernel<<<dim3(D_OUTD / 32, NCOL / 32), dim3(32, 8), 0, stream>>>(stag, out);
    } else {
        sketch_kernel<<<NCOL / 2, 512, 0, stream>>>(xs, out, 0, xcoal);
    }
}

// Round 8
// 270.665 us; speedup vs baseline: 1.6346x; 1.6346x over previous
//
#include <hip/hip_runtime.h>

#define D_IN   1024
#define D_OUTD 8192
#define ORDER  3
#define NCOL   2048

// Persistent device-side tables (rewritten every kernel_launch call).
__device__ float2 g_tw[D_OUTD / 2];      // W_8192^k, k in [0,4096)
__device__ int    g_h[ORDER * D_IN];
__device__ float  g_w[ORDER * D_IN];

__global__ void tw_kernel() {
    int k = blockIdx.x * 256 + threadIdx.x;
    if (k < D_OUTD / 2) {
        double ang = -2.0 * 3.14159265358979323846 * (double)k / (double)D_OUTD;
        g_tw[k] = make_float2((float)cos(ang), (float)sin(ang));
    }
}

__global__ void extract_kernel(const float* __restrict__ hmaps) {
    int idx = blockIdx.x * 256 + threadIdx.x;
    if (idx >= ORDER * D_OUTD * D_IN) return;
    float v = hmaps[idx];
    if (v != 0.0f) {
        int i   = idx % D_IN;
        int rem = idx / D_IN;
        int d   = rem % D_OUTD;
        int o   = rem / D_OUTD;
        g_h[o * D_IN + i] = d;
        g_w[o * D_IN + i] = v;
    }
}

// x [D_IN][N] -> xT [N][D_IN] so sketch blocks read a contiguous 4KB column.
__global__ void xt_kernel(const float* __restrict__ in, float* __restrict__ out) {
    __shared__ float tile[32][33];
    int i0 = blockIdx.x * 32;
    int n0 = blockIdx.y * 32;
    int tx = threadIdx.x;
    int ty = threadIdx.y;
#pragma unroll
    for (int j = 0; j < 32; j += 8)
        tile[ty + j][tx] = in[(i0 + ty + j) * NCOL + n0 + tx];
    __syncthreads();
#pragma unroll
    for (int j = 0; j < 32; j += 8)
        out[(n0 + ty + j) * D_IN + i0 + tx] = tile[tx][ty + j];
}

__device__ __forceinline__ float2 cmul(float2 a, float2 b) {
    return make_float2(a.x * b.x - a.y * b.y, a.x * b.y + a.y * b.x);
}
__device__ __forceinline__ float2 csqr(float2 a) {
    return make_float2(a.x * a.x - a.y * a.y, 2.0f * a.x * a.y);
}
// compile-time 16th roots of unity: e^{-2*pi*i*k/16}, k=0..7
__device__ __forceinline__ float2 c16(int k) {
    constexpr float R[8] = { 1.0f,  0.92387953251128674f,  0.70710678118654757f,  0.38268343236508978f,
                             0.0f, -0.38268343236508978f, -0.70710678118654757f, -0.92387953251128674f };
    constexpr float I[8] = { 0.0f, -0.38268343236508978f, -0.70710678118654757f, -0.92387953251128674f,
                            -1.0f, -0.92387953251128674f, -0.70710678118654757f, -0.38268343236508978f };
    return make_float2(R[k], I[k]);
}

// 4 DIF stages along the register dimension; base twiddle BASE, squared per stage.
#define REG_PHASE_FWD(XR, XI, BASE)                                              \
    {                                                                            \
        float2 ba_ = (BASE);                                                     \
        _Pragma("unroll")                                                        \
        for (int m = 3; m >= 0; --m) {                                           \
            const int half = 1 << m;                                             \
            float2 tw[8];                                                        \
            _Pragma("unroll")                                                    \
            for (int lo = 0; lo < half; ++lo) tw[lo] = cmul(ba_, c16(lo << (3 - m))); \
            _Pragma("unroll")                                                    \
            for (int p = 0; p < 8; ++p) {                                        \
                const int lo = p & (half - 1);                                   \
                const int hi = p >> m;                                           \
                const int j0 = (hi << (m + 1)) + lo;                             \
                const int j1 = j0 + half;                                        \
                const float2 w = tw[lo];                                         \
                float ar = XR[j0], ai = XI[j0];                                  \
                float br = XR[j1], bi = XI[j1];                                  \
                XR[j0] = ar + br; XI[j0] = ai + bi;                              \
                float dr = ar - br, di = ai - bi;                                \
                XR[j1] = dr * w.x - di * w.y;                                    \
                XI[j1] = dr * w.y + di * w.x;                                    \
            }                                                                    \
            if (m) ba_ = csqr(ba_);                                              \
        }                                                                        \
    }

// 4 inverse DIT stages along register dimension; conj twiddles applied inline.
#define REG_PHASE_INV(XR, XI, B8, B4, B2, B1)                                    \
    {                                                                            \
        const float2 bas_[4] = { (B8), (B4), (B2), (B1) };                       \
        _Pragma("unroll")                                                        \
        for (int m = 0; m <= 3; ++m) {                                           \
            const int half = 1 << m;                                             \
            float2 tw[8];                                                        \
            _Pragma("unroll")                                                    \
            for (int lo = 0; lo < half; ++lo) tw[lo] = cmul(bas_[m], c16(lo << (3 - m))); \
            _Pragma("unroll")                                                    \
            for (int p = 0; p < 8; ++p) {                                        \
                const int lo = p & (half - 1);                                   \
                const int hi = p >> m;                                           \
                const int j0 = (hi << (m + 1)) + lo;                             \
                const int j1 = j0 + half;                                        \
                const float2 w = tw[lo];                                         \
                float tr = XR[j1] * w.x + XI[j1] * w.y;                          \
                float ti = XI[j1] * w.x - XR[j1] * w.y;                          \
                XR[j1] = XR[j0] - tr; XI[j1] = XI[j0] - ti;                      \
                XR[j0] += tr; XI[j0] += ti;                                      \
            }                                                                    \
        }                                                                        \
    }

// Forward core: counts in buf (phi-addressed) -> 12 of 13 DIF stages done,
// post-C' values left in XR/XI (slot 32*(t>>1)+2j+e) AND staged in buf for the
// pair-unpack (final stride-1 stage is folded into the unpack read).
#define FWD_CORE(XR, XI)                                                         \
    _Pragma("unroll")                                                            \
    for (int j = 0; j < 16; ++j) { float2 v_ = buf[tA + 512 * j]; XR[j] = v_.x; XI[j] = v_.y; } \
    REG_PHASE_FWD(XR, XI, wt)                                                    \
    _Pragma("unroll")                                                            \
    for (int j = 0; j < 16; ++j) buf[tA + 512 * j] = make_float2(XR[j], XI[j]);  \
    __syncthreads();                                                             \
    _Pragma("unroll")                                                            \
    for (int j = 0; j < 16; ++j) { float2 v_ = buf[bB + 32 * j + (s ^ (j << 1))]; XR[j] = v_.x; XI[j] = v_.y; } \
    REG_PHASE_FWD(XR, XI, bb16)                                                  \
    _Pragma("unroll")                                                            \
    for (int j = 0; j < 16; ++j) buf[bB + 32 * j + (s ^ (j << 1))] = make_float2(XR[j], XI[j]); \
    __syncthreads();                                                             \
    _Pragma("unroll")                                                            \
    for (int j = 0; j < 16; ++j) { float2 v_ = buf[pc + 2 * (j ^ kc)]; XR[j] = v_.x; XI[j] = v_.y; } \
    REG_PHASE_FWD(XR, XI, bc)                                                    \
    _Pragma("unroll")                                                            \
    for (int j = 0; j < 16; ++j) buf[pc + 2 * (j ^ kc)] = make_float2(XR[j], XI[j]); \
    __syncthreads();

// Round-8: R7's no-shfl 3-exchange FFT structure, but peak live register state
// cut from 96 to 64 floats by PARKING one spectrum in the (dead until the end)
// staging region of this block: body A keeps F2[n0] in regs and parks F2[n1];
// after body B the accumulators swap through the park (load F2n1, waitcnt,
// store P0 to the same per-thread slots); body C builds P1; P0 reloads for the
// packed single inverse. R7 spilled 1.46 GB of scratch at the 128-VGPR cap.
__launch_bounds__(512, 2)
__global__ void sketch_kernel(const float* __restrict__ x, float* __restrict__ outbuf,
                              float2* __restrict__ parkbase, int staged, int xcoal) {
    __shared__ __align__(16) float2 buf[D_OUTD];
    const int n0 = 2 * blockIdx.x;
    const int n1 = n0 + 1;
    const int t = threadIdx.x;
    const int e = t & 1;
    const int s = t & 31;
    const int kA = ((t >> 5) & 15) << 1;
    const int tA = t ^ kA;                 // phi(t + 512j) = tA + 512j
    const int bB = 512 * (t >> 5);         // phi(B slot)   = bB + 32j + (s ^ 2j)
    const int kc = (t >> 1) & 15;
    const int pp = 32 * (t >> 1);          // own pair base (swizzled: pp + 2*(j^kc))
    const int pc = pp + e;                 // phi(C slot)   = pc + 2*(j^kc)
    const int qc0 = pp + e;                // TRUE C slot   = qc0 + 2j
    const float sgE = e ? -1.0f : 1.0f;

    float2* pk = parkbase + (size_t)blockIdx.x * D_OUTD;   // 64KB per block

    float xA0, xA1, xB0, xB1;
    if (xcoal) {
        xA0 = x[n0 * D_IN + t]; xA1 = x[n0 * D_IN + t + 512];
        xB0 = x[n1 * D_IN + t]; xB1 = x[n1 * D_IN + t + 512];
    } else {
        xA0 = x[t * NCOL + n0]; xA1 = x[(t + 512) * NCOL + n0];
        xB0 = x[t * NCOL + n1]; xB1 = x[(t + 512) * NCOL + n1];
    }

    // twiddle seeds: wt = W^t (phase A), bb16 = W^(16s) (phase B),
    // bc = W_32^e (phase C'), all other twiddles from squaring chains + c16.
    const float2 wt   = g_tw[t];
    const float2 ws   = g_tw[s];
    const float2 bb16 = csqr(csqr(csqr(csqr(ws))));
    const float2 bc   = e ? make_float2(0.98078528040323044f, -0.19509032201612825f)
                          : make_float2(1.0f, 0.0f);

    float P0r[16], P0i[16], P1r[16], P1i[16];

    // ================= body A: Z = c2[n0] + i*c2[n1] -> F2n0 regs, F2n1 park =====
    {
        float Ar[16], Ai[16];
#pragma unroll
        for (int j = 0; j < 16; ++j) buf[tA + 512 * j] = make_float2(0.0f, 0.0f);
        __syncthreads();
        {
            const int   h0 = g_h[2 * D_IN + t];
            const float w0 = g_w[2 * D_IN + t];
            const int   h1 = g_h[2 * D_IN + t + 512];
            const float w1 = g_w[2 * D_IN + t + 512];
            const int   p0 = h0 ^ (((h0 >> 5) & 15) << 1);
            const int   p1 = h1 ^ (((h1 >> 5) & 15) << 1);
            atomicAdd(&buf[p0].x, w0 * xA0);
            atomicAdd(&buf[p0].y, w0 * xB0);
            atomicAdd(&buf[p1].x, w1 * xA1);
            atomicAdd(&buf[p1].y, w1 * xB1);
        }
        __syncthreads();

        FWD_CORE(Ar, Ai)

#pragma unroll
        for (int j = 0; j < 16; ++j) {
            const int q = qc0 + 2 * j;
            const float4 ov = *reinterpret_cast<const float4*>(&buf[pp + 2 * (j ^ kc)]);
            const int L   = 31 - __clz(q | 1);
            const int pb  = (q ^ ((1 << L) - 1)) & ~1;
            const int pph = pb ^ (((pb >> 5) & 15) << 1);
            const float4 pv = *reinterpret_cast<const float4*>(&buf[pph]);
            const float sgP = (q < 2) ? sgE : -sgE;
            const float ar  = ov.x + sgE * ov.z;       // Z[q]
            const float ai  = ov.y + sgE * ov.w;
            const float pbr =  (pv.x + sgP * pv.z);    // conj(Z[sigma(q)])
            const float pbi = -(pv.y + sgP * pv.w);
            P0r[j] =  0.5f * (ar + pbr);               // F2[n0]
            P0i[j] =  0.5f * (ai + pbi);
            pk[t + 512 * j] = make_float2(0.5f * (ai - pbi),   // F2[n1] -> park
                                          -0.5f * (ar - pbr));
        }
        __syncthreads();
    }

    // ================= body B: Z = c0[n0] + i*c1[n0]; P0 = G0 * F2n0 ============
    {
        float Ar[16], Ai[16];
#pragma unroll
        for (int j = 0; j < 16; ++j) buf[tA + 512 * j] = make_float2(0.0f, 0.0f);
        __syncthreads();
        {
            const int   h0 = g_h[t];            const float w0 = g_w[t];
            const int   h1 = g_h[t + 512];      const float w1 = g_w[t + 512];
            const int   h2 = g_h[D_IN + t];     const float w2 = g_w[D_IN + t];
            const int   h3 = g_h[D_IN + t + 512]; const float w3 = g_w[D_IN + t + 512];
            const int   p0 = h0 ^ (((h0 >> 5) & 15) << 1);
            const int   p1 = h1 ^ (((h1 >> 5) & 15) << 1);
            const int   p2 = h2 ^ (((h2 >> 5) & 15) << 1);
            const int   p3 = h3 ^ (((h3 >> 5) & 15) << 1);
            atomicAdd(&buf[p0].x, w0 * xA0);
            atomicAdd(&buf[p1].x, w1 * xA1);
            atomicAdd(&buf[p2].y, w2 * xA0);
            atomicAdd(&buf[p3].y, w3 * xA1);
        }
        __syncthreads();

        FWD_CORE(Ar, Ai)

#pragma unroll
        for (int j = 0; j < 16; ++j) {
            const int q = qc0 + 2 * j;
            const float4 ov = *reinterpret_cast<const float4*>(&buf[pp + 2 * (j ^ kc)]);
            const int L   = 31 - __clz(q | 1);
            const int pb  = (q ^ ((1 << L) - 1)) & ~1;
            const int pph = pb ^ (((pb >> 5) & 15) << 1);
            const float4 pv = *reinterpret_cast<const float4*>(&buf[pph]);
            const float sgP = (q < 2) ? sgE : -sgE;
            const float ar  = ov.x + sgE * ov.z;
            const float ai  = ov.y + sgE * ov.w;
            const float pbr =  (pv.x + sgP * pv.z);
            const float pbi = -(pv.y + sgP * pv.w);
            const float a2r = ar * ar - ai * ai;
            const float a2i = 2.0f * ar * ai;
            const float b2r = pbr * pbr - pbi * pbi;
            const float b2i = 2.0f * pbr * pbi;
            const float gr =  0.25f * (a2i - b2i);     // G = -i*(A^2 - B^2)/4
            const float gi = -0.25f * (a2r - b2r);
            const float fr = P0r[j], fi = P0i[j];
            P0r[j] = gr * fr - gi * fi;
            P0i[j] = gr * fi + gi * fr;
        }
        __syncthreads();
    }

    // ===== swap accumulators through park: load F2n1 -> P1, then store P0 =======
#pragma unroll
    for (int j = 0; j < 16; ++j) { float2 v = pk[t + 512 * j]; P1r[j] = v.x; P1i[j] = v.y; }
    asm volatile("s_waitcnt vmcnt(0)" ::: "memory");   // loads complete before same-slot stores
#pragma unroll
    for (int j = 0; j < 16; ++j) pk[t + 512 * j] = make_float2(P0r[j], P0i[j]);

    // ================= body C: Z = c0[n1] + i*c1[n1]; P1 = G1 * F2n1 ============
    {
        float Ar[16], Ai[16];
#pragma unroll
        for (int j = 0; j < 16; ++j) buf[tA + 512 * j] = make_float2(0.0f, 0.0f);
        __syncthreads();
        {
            const int   h0 = g_h[t];            const float w0 = g_w[t];
            const int   h1 = g_h[t + 512];      const float w1 = g_w[t + 512];
            const int   h2 = g_h[D_IN + t];     const float w2 = g_w[D_IN + t];
            const int   h3 = g_h[D_IN + t + 512]; const float w3 = g_w[D_IN + t + 512];
            const int   p0 = h0 ^ (((h0 >> 5) & 15) << 1);
            const int   p1 = h1 ^ (((h1 >> 5) & 15) << 1);
            const int   p2 = h2 ^ (((h2 >> 5) & 15) << 1);
            const int   p3 = h3 ^ (((h3 >> 5) & 15) << 1);
            atomicAdd(&buf[p0].x, w0 * xB0);
            atomicAdd(&buf[p1].x, w1 * xB1);
            atomicAdd(&buf[p2].y, w2 * xB0);
            atomicAdd(&buf[p3].y, w3 * xB1);
        }
        __syncthreads();

        FWD_CORE(Ar, Ai)

#pragma unroll
        for (int j = 0; j < 16; ++j) {
            const int q = qc0 + 2 * j;
            const float4 ov = *reinterpret_cast<const float4*>(&buf[pp + 2 * (j ^ kc)]);
            const int L   = 31 - __clz(q | 1);
            const int pb  = (q ^ ((1 << L) - 1)) & ~1;
            const int pph = pb ^ (((pb >> 5) & 15) << 1);
            const float4 pv = *reinterpret_cast<const float4*>(&buf[pph]);
            const float sgP = (q < 2) ? sgE : -sgE;
            const float ar  = ov.x + sgE * ov.z;
            const float ai  = ov.y + sgE * ov.w;
            const float pbr =  (pv.x + sgP * pv.z);
            const float pbi = -(pv.y + sgP * pv.w);
            const float a2r = ar * ar - ai * ai;
            const float a2i = 2.0f * ar * ai;
            const float b2r = pbr * pbr - pbi * pbi;
            const float b2i = 2.0f * pbr * pbi;
            const float gr =  0.25f * (a2i - b2i);
            const float gi = -0.25f * (a2r - b2r);
            const float fr = P1r[j], fi = P1i[j];
            P1r[j] = gr * fr - gi * fi;
            P1i[j] = gr * fi + gi * fr;
        }
        __syncthreads();
    }

    // ===== reload P0, pack Q = P0 + i*P1, one inverse for both columns ==========
    float Qr[16], Qi[16];
#pragma unroll
    for (int j = 0; j < 16; ++j) {
        float2 v = pk[t + 512 * j];
        Qr[j] = v.x - P1i[j];
        Qi[j] = v.y + P1r[j];
    }

    // stride-1 inverse stage (twiddle-free): pairs are lanes (t, t^1)
#pragma unroll
    for (int j = 0; j < 16; ++j) {
        const float orr = __shfl_xor(Qr[j], 1, 64);
        const float oii = __shfl_xor(Qi[j], 1, 64);
        Qr[j] = orr + sgE * Qr[j];
        Qi[j] = oii + sgE * Qi[j];
    }

    // C'-inv: strides 2..16
    {
        const float2 bc2 = csqr(bc), bc4 = csqr(bc2), bc8 = csqr(bc4);
        REG_PHASE_INV(Qr, Qi, bc8, bc4, bc2, bc)
    }

    // ex2-inv: C layout -> B layout
#pragma unroll
    for (int j = 0; j < 16; ++j) buf[pc + 2 * (j ^ kc)] = make_float2(Qr[j], Qi[j]);
    __syncthreads();
#pragma unroll
    for (int j = 0; j < 16; ++j) { float2 v_ = buf[bB + 32 * j + (s ^ (j << 1))]; Qr[j] = v_.x; Qi[j] = v_.y; }

    // B-inv: strides 32..256
    {
        const float2 bb32 = csqr(bb16), bb64 = csqr(bb32), bb128 = csqr(bb64);
        REG_PHASE_INV(Qr, Qi, bb128, bb64, bb32, bb16)
    }

    // ex1-inv: B layout -> A layout
#pragma unroll
    for (int j = 0; j < 16; ++j) buf[bB + 32 * j + (s ^ (j << 1))] = make_float2(Qr[j], Qi[j]);
    __syncthreads();
#pragma unroll
    for (int j = 0; j < 16; ++j) { float2 v_ = buf[tA + 512 * j]; Qr[j] = v_.x; Qi[j] = v_.y; }

    // A-inv: strides 512..4096
    {
        const float2 wa2 = csqr(wt), wa4 = csqr(wa2), wa8 = csqr(wa4);
        REG_PHASE_INV(Qr, Qi, wa8, wa4, wa2, wt)
    }

    const float scale = 1.0f / (float)D_OUTD;
    if (staged) {
#pragma unroll
        for (int j = 0; j < 16; ++j) {
            outbuf[n0 * D_OUTD + t + 512 * j] = Qr[j] * scale;   // Re -> column n0
            outbuf[n1 * D_OUTD + t + 512 * j] = Qi[j] * scale;   // Im -> column n1
        }
    } else {
#pragma unroll
        for (int j = 0; j < 16; ++j) {
            outbuf[(t + 512 * j) * NCOL + n0] = Qr[j] * scale;
            outbuf[(t + 512 * j) * NCOL + n1] = Qi[j] * scale;
        }
    }
}

// [N][D_out] -> [D_out][N], 32x32 tiles
__global__ void transpose_kernel(const float* __restrict__ in, float* __restrict__ out) {
    __shared__ float tile[32][33];
    int d0 = blockIdx.x * 32;
    int n0 = blockIdx.y * 32;
    int tx = threadIdx.x;
    int ty = threadIdx.y;
#pragma unroll
    for (int j = 0; j < 32; j += 8)
        tile[ty + j][tx] = in[(n0 + ty + j) * D_OUTD + d0 + tx];
    __syncthreads();
#pragma unroll
    for (int j = 0; j < 32; j += 8)
        out[(d0 + ty + j) * NCOL + n0 + tx] = tile[tx][ty + j];
}

extern "C" void kernel_launch(void* const* d_in, const int* in_sizes, int n_in,
                              void* d_out, int out_size, void* d_ws, size_t ws_size,
                              hipStream_t stream) {
    (void)in_sizes; (void)n_in; (void)out_size;
    const float* x     = (const float*)d_in[0];
    const float* hmaps = (const float*)d_in[1];
    float* out = (float*)d_out;

    tw_kernel<<<(D_OUTD / 2 + 255) / 256, 256, 0, stream>>>();
    extract_kernel<<<(ORDER * D_OUTD * D_IN + 255) / 256, 256, 0, stream>>>(hmaps);

    const size_t stage_bytes = (size_t)NCOL * D_OUTD * sizeof(float);
    const size_t xt_bytes    = (size_t)NCOL * D_IN * sizeof(float);

    const float* xs = x;
    int xcoal = 0;
    if (ws_size >= stage_bytes + xt_bytes) {
        float* xT = (float*)((char*)d_ws + stage_bytes);
        xt_kernel<<<dim3(D_IN / 32, NCOL / 32), dim3(32, 8), 0, stream>>>(x, xT);
        xs = xT;
        xcoal = 1;
    }

    if (ws_size >= stage_bytes) {
        // staged: park region == each block's (dead until the end) staging share
        float* stag = (float*)d_ws;
        sketch_kernel<<<NCOL / 2, 512, 0, stream>>>(xs, stag, (float2*)stag, 1, xcoal);
        transpose_kernel<<<dim3(D_OUTD / 32, NCOL / 32), dim3(32, 8), 0, stream>>>(stag, out);
    } else {
        // fallback: strided direct write; park lives in d_ws (needs 64MB)
        sketch_kernel<<<NCOL / 2, 512, 0, stream>>>(xs, out, (float2*)d_ws, 0, xcoal);
    }
}

// Round 9
// 255.821 us; speedup vs baseline: 1.7294x; 1.0580x over previous
//
#include <hip/hip_runtime.h>

#define D_IN   1024
#define D_OUTD 8192
#define ORDER  3
#define NCOL   2048

// Persistent device-side tables (rewritten every kernel_launch call).
__device__ float2 g_tw[D_OUTD / 2];      // W_8192^k, k in [0,4096)
__device__ int    g_h[ORDER * D_IN];
__device__ float  g_w[ORDER * D_IN];

__global__ void tw_kernel() {
    int k = blockIdx.x * 256 + threadIdx.x;
    if (k < D_OUTD / 2) {
        double ang = -2.0 * 3.14159265358979323846 * (double)k / (double)D_OUTD;
        g_tw[k] = make_float2((float)cos(ang), (float)sin(ang));
    }
}

__global__ void extract_kernel(const float* __restrict__ hmaps) {
    int idx = blockIdx.x * 256 + threadIdx.x;
    if (idx >= ORDER * D_OUTD * D_IN) return;
    float v = hmaps[idx];
    if (v != 0.0f) {
        int i   = idx % D_IN;
        int rem = idx / D_IN;
        int d   = rem % D_OUTD;
        int o   = rem / D_OUTD;
        g_h[o * D_IN + i] = d;
        g_w[o * D_IN + i] = v;
    }
}

// x [D_IN][N] -> xT [N][D_IN] so sketch blocks read a contiguous 4KB column.
__global__ void xt_kernel(const float* __restrict__ in, float* __restrict__ out) {
    __shared__ float tile[32][33];
    int i0 = blockIdx.x * 32;
    int n0 = blockIdx.y * 32;
    int tx = threadIdx.x;
    int ty = threadIdx.y;
#pragma unroll
    for (int j = 0; j < 32; j += 8)
        tile[ty + j][tx] = in[(i0 + ty + j) * NCOL + n0 + tx];
    __syncthreads();
#pragma unroll
    for (int j = 0; j < 32; j += 8)
        out[(n0 + ty + j) * D_IN + i0 + tx] = tile[tx][ty + j];
}

__device__ __forceinline__ float2 cmul(float2 a, float2 b) {
    return make_float2(a.x * b.x - a.y * b.y, a.x * b.y + a.y * b.x);
}
__device__ __forceinline__ float2 csqr(float2 a) {
    return make_float2(a.x * a.x - a.y * a.y, 2.0f * a.x * a.y);
}
// compile-time 16th roots of unity: e^{-2*pi*i*k/16}, k=0..7
__device__ __forceinline__ float2 c16(int k) {
    constexpr float R[8] = { 1.0f,  0.92387953251128674f,  0.70710678118654757f,  0.38268343236508978f,
                             0.0f, -0.38268343236508978f, -0.70710678118654757f, -0.92387953251128674f };
    constexpr float I[8] = { 0.0f, -0.38268343236508978f, -0.70710678118654757f, -0.92387953251128674f,
                            -1.0f, -0.92387953251128674f, -0.70710678118654757f, -0.38268343236508978f };
    return make_float2(R[k], I[k]);
}

// 4 DIF stages along the register dimension; base twiddle BASE, squared per stage.
#define REG_PHASE_FWD(XR, XI, BASE)                                              \
    {                                                                            \
        float2 ba_ = (BASE);                                                     \
        _Pragma("unroll")                                                        \
        for (int m = 3; m >= 0; --m) {                                           \
            const int half = 1 << m;                                             \
            float2 tw[8];                                                        \
            _Pragma("unroll")                                                    \
            for (int lo = 0; lo < half; ++lo) tw[lo] = cmul(ba_, c16(lo << (3 - m))); \
            _Pragma("unroll")                                                    \
            for (int p = 0; p < 8; ++p) {                                        \
                const int lo = p & (half - 1);                                   \
                const int hi = p >> m;                                           \
                const int j0 = (hi << (m + 1)) + lo;                             \
                const int j1 = j0 + half;                                        \
                const float2 w = tw[lo];                                         \
                float ar = XR[j0], ai = XI[j0];                                  \
                float br = XR[j1], bi = XI[j1];                                  \
                XR[j0] = ar + br; XI[j0] = ai + bi;                              \
                float dr = ar - br, di = ai - bi;                                \
                XR[j1] = dr * w.x - di * w.y;                                    \
                XI[j1] = dr * w.y + di * w.x;                                    \
            }                                                                    \
            if (m) ba_ = csqr(ba_);                                              \
        }                                                                        \
    }

// 4 inverse DIT stages along register dimension; conj twiddles applied inline.
#define REG_PHASE_INV(XR, XI, B8, B4, B2, B1)                                    \
    {                                                                            \
        const float2 bas_[4] = { (B8), (B4), (B2), (B1) };                       \
        _Pragma("unroll")                                                        \
        for (int m = 0; m <= 3; ++m) {                                           \
            const int half = 1 << m;                                             \
            float2 tw[8];                                                        \
            _Pragma("unroll")                                                    \
            for (int lo = 0; lo < half; ++lo) tw[lo] = cmul(bas_[m], c16(lo << (3 - m))); \
            _Pragma("unroll")                                                    \
            for (int p = 0; p < 8; ++p) {                                        \
                const int lo = p & (half - 1);                                   \
                const int hi = p >> m;                                           \
                const int j0 = (hi << (m + 1)) + lo;                             \
                const int j1 = j0 + half;                                        \
                const float2 w = tw[lo];                                         \
                float tr = XR[j1] * w.x + XI[j1] * w.y;                          \
                float ti = XI[j1] * w.x - XR[j1] * w.y;                          \
                XR[j1] = XR[j0] - tr; XI[j1] = XI[j0] - ti;                      \
                XR[j0] += tr; XI[j0] += ti;                                      \
            }                                                                    \
        }                                                                        \
    }

// Full forward FFT: counts in buf (phi-addressed) -> FINAL spectrum.
// Phases: A (strides 4096..512, reg) -> ex -> B (256..32, reg) -> ex ->
// C' (16..2, reg) -> stride-1 via ONE shfl_xor(1) butterfly -> stage final
// spectrum at phi(q) (C layout). After the trailing sync, partner slots are
// readable for the Hermitian unpack with a single b64 read per j (R7's float4
// pair-unpack caused the 128-VGPR spill; this keeps per-j temps to 2 floats).
#define FWD_CORE(XR, XI)                                                         \
    _Pragma("unroll")                                                            \
    for (int j = 0; j < 16; ++j) { float2 v_ = buf[tA + 512 * j]; XR[j] = v_.x; XI[j] = v_.y; } \
    REG_PHASE_FWD(XR, XI, wt)                                                    \
    _Pragma("unroll")                                                            \
    for (int j = 0; j < 16; ++j) buf[tA + 512 * j] = make_float2(XR[j], XI[j]);  \
    __syncthreads();                                                             \
    _Pragma("unroll")                                                            \
    for (int j = 0; j < 16; ++j) { float2 v_ = buf[bB + 32 * j + (s ^ (j << 1))]; XR[j] = v_.x; XI[j] = v_.y; } \
    REG_PHASE_FWD(XR, XI, bb16)                                                  \
    _Pragma("unroll")                                                            \
    for (int j = 0; j < 16; ++j) buf[bB + 32 * j + (s ^ (j << 1))] = make_float2(XR[j], XI[j]); \
    __syncthreads();                                                             \
    _Pragma("unroll")                                                            \
    for (int j = 0; j < 16; ++j) { float2 v_ = buf[pc + 2 * (j ^ kc)]; XR[j] = v_.x; XI[j] = v_.y; } \
    REG_PHASE_FWD(XR, XI, bc)                                                    \
    _Pragma("unroll")                                                            \
    for (int j = 0; j < 16; ++j) {                                               \
        const float pr_ = __shfl_xor(XR[j], 1, 64);                              \
        const float pi_ = __shfl_xor(XI[j], 1, 64);                              \
        XR[j] = pr_ + sgE * XR[j];                                               \
        XI[j] = pi_ + sgE * XI[j];                                               \
    }                                                                            \
    _Pragma("unroll")                                                            \
    for (int j = 0; j < 16; ++j) buf[pc + 2 * (j ^ kc)] = make_float2(XR[j], XI[j]); \
    __syncthreads();

// Round-9: R6's register profile (P0+P1 in regs, no park, no float4 unpack)
// combined with R7's DS savings (3 exchanges, one shfl stage instead of 160
// swizzles/body, all LDS traffic b64 through involution phi).
__launch_bounds__(512, 2)
__global__ void sketch_kernel(const float* __restrict__ x, float* __restrict__ outbuf,
                              int staged, int xcoal) {
    __shared__ __align__(16) float2 buf[D_OUTD];
    const int n0 = 2 * blockIdx.x;
    const int n1 = n0 + 1;
    const int t = threadIdx.x;
    const int e = t & 1;
    const int s = t & 31;
    const int kA = ((t >> 5) & 15) << 1;
    const int tA = t ^ kA;                 // phi(t + 512j) = tA + 512j
    const int bB = 512 * (t >> 5);         // phi(B slot)   = bB + 32j + (s ^ 2j)
    const int kc = (t >> 1) & 15;
    const int pp = 32 * (t >> 1);
    const int pc = pp + e;                 // phi(C slot)   = pc + 2*(j^kc)
    const int qc0 = pp + e;                // TRUE C slot   = qc0 + 2j
    const float sgE = e ? -1.0f : 1.0f;

    float xA0, xA1, xB0, xB1;
    if (xcoal) {
        xA0 = x[n0 * D_IN + t]; xA1 = x[n0 * D_IN + t + 512];
        xB0 = x[n1 * D_IN + t]; xB1 = x[n1 * D_IN + t + 512];
    } else {
        xA0 = x[t * NCOL + n0]; xA1 = x[(t + 512) * NCOL + n0];
        xB0 = x[t * NCOL + n1]; xB1 = x[(t + 512) * NCOL + n1];
    }

    // twiddle seeds: wt = W^t (phase A), bb16 = W^(16s) (phase B),
    // bc = W_32^e (phase C'); everything else from squaring chains + c16.
    const float2 wt   = g_tw[t];
    const float2 ws   = g_tw[s];
    const float2 bb16 = csqr(csqr(csqr(csqr(ws))));
    const float2 bc   = e ? make_float2(0.98078528040323044f, -0.19509032201612825f)
                          : make_float2(1.0f, 0.0f);

    float P0r[16], P0i[16], P1r[16], P1i[16];

    // ================= body A: Z = c2[n0] + i*c2[n1] -> split F2 =================
    {
        float Ar[16], Ai[16];
#pragma unroll
        for (int j = 0; j < 16; ++j) buf[tA + 512 * j] = make_float2(0.0f, 0.0f);
        __syncthreads();
        {
            const int   h0 = g_h[2 * D_IN + t];
            const float w0 = g_w[2 * D_IN + t];
            const int   h1 = g_h[2 * D_IN + t + 512];
            const float w1 = g_w[2 * D_IN + t + 512];
            const int   p0 = h0 ^ (((h0 >> 5) & 15) << 1);
            const int   p1 = h1 ^ (((h1 >> 5) & 15) << 1);
            atomicAdd(&buf[p0].x, w0 * xA0);
            atomicAdd(&buf[p0].y, w0 * xB0);
            atomicAdd(&buf[p1].x, w1 * xA1);
            atomicAdd(&buf[p1].y, w1 * xB1);
        }
        __syncthreads();

        FWD_CORE(Ar, Ai)

        // Hermitian split: F2n0 = (Z+B)/2 -> P0, F2n1 = (Z-B)/(2i) -> P1,
        // B = conj(Z[sigma(q)]), one b64 partner read per j.
#pragma unroll
        for (int j = 0; j < 16; ++j) {
            const int q  = qc0 + 2 * j;
            const int L  = 31 - __clz(q | 1);
            const int sq = (q < 2) ? q : (q ^ ((1 << L) - 1));
            const int ps = sq ^ (((sq >> 5) & 15) << 1);
            const float2 pv = buf[ps];
            const float pbr =  pv.x;
            const float pbi = -pv.y;
            P0r[j] =  0.5f * (Ar[j] + pbr);
            P0i[j] =  0.5f * (Ai[j] + pbi);
            P1r[j] =  0.5f * (Ai[j] - pbi);
            P1i[j] = -0.5f * (Ar[j] - pbr);
        }
        __syncthreads();
    }

    // ================= body B: Z = c0[n0] + i*c1[n0]; P0 *= G0 =================
    {
        float Ar[16], Ai[16];
#pragma unroll
        for (int j = 0; j < 16; ++j) buf[tA + 512 * j] = make_float2(0.0f, 0.0f);
        __syncthreads();
        {
            const int   h0 = g_h[t];              const float w0 = g_w[t];
            const int   h1 = g_h[t + 512];        const float w1 = g_w[t + 512];
            const int   h2 = g_h[D_IN + t];       const float w2 = g_w[D_IN + t];
            const int   h3 = g_h[D_IN + t + 512]; const float w3 = g_w[D_IN + t + 512];
            const int   p0 = h0 ^ (((h0 >> 5) & 15) << 1);
            const int   p1 = h1 ^ (((h1 >> 5) & 15) << 1);
            const int   p2 = h2 ^ (((h2 >> 5) & 15) << 1);
            const int   p3 = h3 ^ (((h3 >> 5) & 15) << 1);
            atomicAdd(&buf[p0].x, w0 * xA0);
            atomicAdd(&buf[p1].x, w1 * xA1);
            atomicAdd(&buf[p2].y, w2 * xA0);
            atomicAdd(&buf[p3].y, w3 * xA1);
        }
        __syncthreads();

        FWD_CORE(Ar, Ai)

#pragma unroll
        for (int j = 0; j < 16; ++j) {
            const int q  = qc0 + 2 * j;
            const int L  = 31 - __clz(q | 1);
            const int sq = (q < 2) ? q : (q ^ ((1 << L) - 1));
            const int ps = sq ^ (((sq >> 5) & 15) << 1);
            const float2 pv = buf[ps];
            const float pbr =  pv.x;
            const float pbi = -pv.y;
            const float a2r = Ar[j] * Ar[j] - Ai[j] * Ai[j];
            const float a2i = 2.0f * Ar[j] * Ai[j];
            const float b2r = pbr * pbr - pbi * pbi;
            const float b2i = 2.0f * pbr * pbi;
            const float gr =  0.25f * (a2i - b2i);   // G = -i*(A^2 - B^2)/4
            const float gi = -0.25f * (a2r - b2r);
            const float fr = P0r[j], fi = P0i[j];
            P0r[j] = gr * fr - gi * fi;
            P0i[j] = gr * fi + gi * fr;
        }
        __syncthreads();
    }

    // ================= body C: Z = c0[n1] + i*c1[n1]; P1 *= G1 =================
    {
        float Ar[16], Ai[16];
#pragma unroll
        for (int j = 0; j < 16; ++j) buf[tA + 512 * j] = make_float2(0.0f, 0.0f);
        __syncthreads();
        {
            const int   h0 = g_h[t];              const float w0 = g_w[t];
            const int   h1 = g_h[t + 512];        const float w1 = g_w[t + 512];
            const int   h2 = g_h[D_IN + t];       const float w2 = g_w[D_IN + t];
            const int   h3 = g_h[D_IN + t + 512]; const float w3 = g_w[D_IN + t + 512];
            const int   p0 = h0 ^ (((h0 >> 5) & 15) << 1);
            const int   p1 = h1 ^ (((h1 >> 5) & 15) << 1);
            const int   p2 = h2 ^ (((h2 >> 5) & 15) << 1);
            const int   p3 = h3 ^ (((h3 >> 5) & 15) << 1);
            atomicAdd(&buf[p0].x, w0 * xB0);
            atomicAdd(&buf[p1].x, w1 * xB1);
            atomicAdd(&buf[p2].y, w2 * xB0);
            atomicAdd(&buf[p3].y, w3 * xB1);
        }
        __syncthreads();

        FWD_CORE(Ar, Ai)

#pragma unroll
        for (int j = 0; j < 16; ++j) {
            const int q  = qc0 + 2 * j;
            const int L  = 31 - __clz(q | 1);
            const int sq = (q < 2) ? q : (q ^ ((1 << L) - 1));
            const int ps = sq ^ (((sq >> 5) & 15) << 1);
            const float2 pv = buf[ps];
            const float pbr =  pv.x;
            const float pbi = -pv.y;
            const float a2r = Ar[j] * Ar[j] - Ai[j] * Ai[j];
            const float a2i = 2.0f * Ar[j] * Ai[j];
            const float b2r = pbr * pbr - pbi * pbi;
            const float b2i = 2.0f * pbr * pbi;
            const float gr =  0.25f * (a2i - b2i);
            const float gi = -0.25f * (a2r - b2r);
            const float fr = P1r[j], fi = P1i[j];
            P1r[j] = gr * fr - gi * fi;
            P1i[j] = gr * fi + gi * fr;
        }
        __syncthreads();
    }

    // ===== pack Q = P0 + i*P1, one inverse for both columns =====================
    float Qr[16], Qi[16];
#pragma unroll
    for (int j = 0; j < 16; ++j) {
        Qr[j] = P0r[j] - P1i[j];
        Qi[j] = P0i[j] + P1r[j];
    }

    // stride-1 inverse stage (twiddle-free): pairs are lanes (t, t^1)
#pragma unroll
    for (int j = 0; j < 16; ++j) {
        const float orr = __shfl_xor(Qr[j], 1, 64);
        const float oii = __shfl_xor(Qi[j], 1, 64);
        Qr[j] = orr + sgE * Qr[j];
        Qi[j] = oii + sgE * Qi[j];
    }

    // C'-inv: strides 2..16
    {
        const float2 bc2 = csqr(bc), bc4 = csqr(bc2), bc8 = csqr(bc4);
        REG_PHASE_INV(Qr, Qi, bc8, bc4, bc2, bc)
    }

    // ex2-inv: C layout -> B layout
#pragma unroll
    for (int j = 0; j < 16; ++j) buf[pc + 2 * (j ^ kc)] = make_float2(Qr[j], Qi[j]);
    __syncthreads();
#pragma unroll
    for (int j = 0; j < 16; ++j) { float2 v_ = buf[bB + 32 * j + (s ^ (j << 1))]; Qr[j] = v_.x; Qi[j] = v_.y; }

    // B-inv: strides 32..256
    {
        const float2 bb32 = csqr(bb16), bb64 = csqr(bb32), bb128 = csqr(bb64);
        REG_PHASE_INV(Qr, Qi, bb128, bb64, bb32, bb16)
    }

    // ex1-inv: B layout -> A layout
#pragma unroll
    for (int j = 0; j < 16; ++j) buf[bB + 32 * j + (s ^ (j << 1))] = make_float2(Qr[j], Qi[j]);
    __syncthreads();
#pragma unroll
    for (int j = 0; j < 16; ++j) { float2 v_ = buf[tA + 512 * j]; Qr[j] = v_.x; Qi[j] = v_.y; }

    // A-inv: strides 512..4096
    {
        const float2 wa2 = csqr(wt), wa4 = csqr(wa2), wa8 = csqr(wa4);
        REG_PHASE_INV(Qr, Qi, wa8, wa4, wa2, wt)
    }

    const float scale = 1.0f / (float)D_OUTD;
    if (staged) {
#pragma unroll
        for (int j = 0; j < 16; ++j) {
            outbuf[n0 * D_OUTD + t + 512 * j] = Qr[j] * scale;   // Re -> column n0
            outbuf[n1 * D_OUTD + t + 512 * j] = Qi[j] * scale;   // Im -> column n1
        }
    } else {
#pragma unroll
        for (int j = 0; j < 16; ++j) {
            outbuf[(t + 512 * j) * NCOL + n0] = Qr[j] * scale;
            outbuf[(t + 512 * j) * NCOL + n1] = Qi[j] * scale;
        }
    }
}

// [N][D_out] -> [D_out][N], 32x32 tiles
__global__ void transpose_kernel(const float* __restrict__ in, float* __restrict__ out) {
    __shared__ float tile[32][33];
    int d0 = blockIdx.x * 32;
    int n0 = blockIdx.y * 32;
    int tx = threadIdx.x;
    int ty = threadIdx.y;
#pragma unroll
    for (int j = 0; j < 32; j += 8)
        tile[ty + j][tx] = in[(n0 + ty + j) * D_OUTD + d0 + tx];
    __syncthreads();
#pragma unroll
    for (int j = 0; j < 32; j += 8)
        out[(d0 + ty + j) * NCOL + n0 + tx] = tile[tx][ty + j];
}

extern "C" void kernel_launch(void* const* d_in, const int* in_sizes, int n_in,
                              void* d_out, int out_size, void* d_ws, size_t ws_size,
                              hipStream_t stream) {
    (void)in_sizes; (void)n_in; (void)out_size;
    const float* x     = (const float*)d_in[0];
    const float* hmaps = (const float*)d_in[1];
    float* out = (float*)d_out;

    tw_kernel<<<(D_OUTD / 2 + 255) / 256, 256, 0, stream>>>();
    extract_kernel<<<(ORDER * D_OUTD * D_IN + 255) / 256, 256, 0, stream>>>(hmaps);

    const size_t stage_bytes = (size_t)NCOL * D_OUTD * sizeof(float);
    const size_t xt_bytes    = (size_t)NCOL * D_IN * sizeof(float);

    const float* xs = x;
    int xcoal = 0;
    if (ws_size >= stage_bytes + xt_bytes) {
        float* xT = (float*)((char*)d_ws + stage_bytes);
        xt_kernel<<<dim3(D_IN / 32, NCOL / 32), dim3(32, 8), 0, stream>>>(x, xT);
        xs = xT;
        xcoal = 1;
    }

    if (ws_size >= stage_bytes) {
        float* stag = (float*)d_ws;
        sketch_kernel<<<NCOL / 2, 512, 0, stream>>>(xs, stag, 1, xcoal);
        transpose_kernel<<<dim3(D_OUTD / 32, NCOL / 32), dim3(32, 8), 0, stream>>>(stag, out);
    } else {
        sketch_kernel<<<NCOL / 2, 512, 0, stream>>>(xs, out, 0, xcoal);
    }
}

// Round 10
// 254.563 us; speedup vs baseline: 1.7380x; 1.0049x over previous
//
#include <hip/hip_runtime.h>

#define D_IN   1024
#define D_OUTD 8192
#define ORDER  3
#define NCOL   2048

// Persistent device-side tables (rewritten every kernel_launch call).
__device__ float2 g_tw[D_OUTD / 2];      // W_8192^k, k in [0,4096)
__device__ int    g_h[ORDER * D_IN];
__device__ float  g_w[ORDER * D_IN];

__global__ void tw_kernel() {
    int k = blockIdx.x * 256 + threadIdx.x;
    if (k < D_OUTD / 2) {
        double ang = -2.0 * 3.14159265358979323846 * (double)k / (double)D_OUTD;
        g_tw[k] = make_float2((float)cos(ang), (float)sin(ang));
    }
}

__global__ void extract_kernel(const float* __restrict__ hmaps) {
    int idx = blockIdx.x * 256 + threadIdx.x;
    if (idx >= ORDER * D_OUTD * D_IN) return;
    float v = hmaps[idx];
    if (v != 0.0f) {
        int i   = idx % D_IN;
        int rem = idx / D_IN;
        int d   = rem % D_OUTD;
        int o   = rem / D_OUTD;
        g_h[o * D_IN + i] = d;
        g_w[o * D_IN + i] = v;
    }
}

// x [D_IN][N] -> xT [N][D_IN] so sketch blocks read a contiguous 4KB column.
__global__ void xt_kernel(const float* __restrict__ in, float* __restrict__ out) {
    __shared__ float tile[32][33];
    int i0 = blockIdx.x * 32;
    int n0 = blockIdx.y * 32;
    int tx = threadIdx.x;
    int ty = threadIdx.y;
#pragma unroll
    for (int j = 0; j < 32; j += 8)
        tile[ty + j][tx] = in[(i0 + ty + j) * NCOL + n0 + tx];
    __syncthreads();
#pragma unroll
    for (int j = 0; j < 32; j += 8)
        out[(n0 + ty + j) * D_IN + i0 + tx] = tile[tx][ty + j];
}

__device__ __forceinline__ float2 cmul(float2 a, float2 b) {
    return make_float2(a.x * b.x - a.y * b.y, a.x * b.y + a.y * b.x);
}
__device__ __forceinline__ float2 csqr(float2 a) {
    return make_float2(a.x * a.x - a.y * a.y, 2.0f * a.x * a.y);
}
// compile-time 16th roots of unity: e^{-2*pi*i*k/16}, k=0..7
__device__ __forceinline__ float2 c16(int k) {
    constexpr float R[8] = { 1.0f,  0.92387953251128674f,  0.70710678118654757f,  0.38268343236508978f,
                             0.0f, -0.38268343236508978f, -0.70710678118654757f, -0.92387953251128674f };
    constexpr float I[8] = { 0.0f, -0.38268343236508978f, -0.70710678118654757f, -0.92387953251128674f,
                            -1.0f, -0.92387953251128674f, -0.70710678118654757f, -0.38268343236508978f };
    return make_float2(R[k], I[k]);
}

// 4 DIF stages along the register dimension; base twiddle BASE, squared per stage.
#define REG_PHASE_FWD(XR, XI, BASE)                                              \
    {                                                                            \
        float2 ba_ = (BASE);                                                     \
        _Pragma("unroll")                                                        \
        for (int m = 3; m >= 0; --m) {                                           \
            const int half = 1 << m;                                             \
            float2 tw[8];                                                        \
            _Pragma("unroll")                                                    \
            for (int lo = 0; lo < half; ++lo) tw[lo] = cmul(ba_, c16(lo << (3 - m))); \
            _Pragma("unroll")                                                    \
            for (int p = 0; p < 8; ++p) {                                        \
                const int lo = p & (half - 1);                                   \
                const int hi = p >> m;                                           \
                const int j0 = (hi << (m + 1)) + lo;                             \
                const int j1 = j0 + half;                                        \
                const float2 w = tw[lo];                                         \
                float ar = XR[j0], ai = XI[j0];                                  \
                float br = XR[j1], bi = XI[j1];                                  \
                XR[j0] = ar + br; XI[j0] = ai + bi;                              \
                float dr = ar - br, di = ai - bi;                                \
                XR[j1] = dr * w.x - di * w.y;                                    \
                XI[j1] = dr * w.y + di * w.x;                                    \
            }                                                                    \
            if (m) ba_ = csqr(ba_);                                              \
        }                                                                        \
    }

// 4 inverse DIT stages along register dimension; conj twiddles applied inline.
#define REG_PHASE_INV(XR, XI, B8, B4, B2, B1)                                    \
    {                                                                            \
        const float2 bas_[4] = { (B8), (B4), (B2), (B1) };                       \
        _Pragma("unroll")                                                        \
        for (int m = 0; m <= 3; ++m) {                                           \
            const int half = 1 << m;                                             \
            float2 tw[8];                                                        \
            _Pragma("unroll")                                                    \
            for (int lo = 0; lo < half; ++lo) tw[lo] = cmul(bas_[m], c16(lo << (3 - m))); \
            _Pragma("unroll")                                                    \
            for (int p = 0; p < 8; ++p) {                                        \
                const int lo = p & (half - 1);                                   \
                const int hi = p >> m;                                           \
                const int j0 = (hi << (m + 1)) + lo;                             \
                const int j1 = j0 + half;                                        \
                const float2 w = tw[lo];                                         \
                float tr = XR[j1] * w.x + XI[j1] * w.y;                          \
                float ti = XI[j1] * w.x - XR[j1] * w.y;                          \
                XR[j1] = XR[j0] - tr; XI[j1] = XI[j0] - ti;                      \
                XR[j0] += tr; XI[j0] += ti;                                      \
            }                                                                    \
        }                                                                        \
    }

// Full forward FFT: counts in buf (phi-addressed) -> FINAL spectrum.
// Phases: A (strides 4096..512, reg) -> ex -> B (256..32, reg) -> ex ->
// C' (16..2, reg) -> stride-1 via ONE shfl_xor(1) butterfly -> stage final
// spectrum at phi(q) (C layout) for the Hermitian-partner reads.
#define FWD_CORE(XR, XI)                                                         \
    _Pragma("unroll")                                                            \
    for (int j = 0; j < 16; ++j) { float2 v_ = buf[tA + 512 * j]; XR[j] = v_.x; XI[j] = v_.y; } \
    REG_PHASE_FWD(XR, XI, wt)                                                    \
    _Pragma("unroll")                                                            \
    for (int j = 0; j < 16; ++j) buf[tA + 512 * j] = make_float2(XR[j], XI[j]);  \
    __syncthreads();                                                             \
    _Pragma("unroll")                                                            \
    for (int j = 0; j < 16; ++j) { float2 v_ = buf[bB + 32 * j + (s ^ (j << 1))]; XR[j] = v_.x; XI[j] = v_.y; } \
    REG_PHASE_FWD(XR, XI, bb16)                                                  \
    _Pragma("unroll")                                                            \
    for (int j = 0; j < 16; ++j) buf[bB + 32 * j + (s ^ (j << 1))] = make_float2(XR[j], XI[j]); \
    __syncthreads();                                                             \
    _Pragma("unroll")                                                            \
    for (int j = 0; j < 16; ++j) { float2 v_ = buf[pc + 2 * (j ^ kc)]; XR[j] = v_.x; XI[j] = v_.y; } \
    REG_PHASE_FWD(XR, XI, bc)                                                    \
    _Pragma("unroll")                                                            \
    for (int j = 0; j < 16; ++j) {                                               \
        const float pr_ = __shfl_xor(XR[j], 1, 64);                              \
        const float pi_ = __shfl_xor(XI[j], 1, 64);                              \
        XR[j] = pr_ + sgE * XR[j];                                               \
        XI[j] = pi_ + sgE * XI[j];                                               \
    }                                                                            \
    _Pragma("unroll")                                                            \
    for (int j = 0; j < 16; ++j) buf[pc + 2 * (j ^ kc)] = make_float2(XR[j], XI[j]); \
    __syncthreads();

// Round-10: R9 unchanged EXCEPT __launch_bounds__(512, 1). R7/R8/R9 all spilled
// at the (512,2) 128-VGPR cap (FETCH 148-514 MB of scratch). Relaxing the cap
// trades occupancy (2 blocks/CU -> 1) for zero spill; the kernel is DS-pipe
// bound, and 8 waves issuing 16-deep DS bursts keep the (per-CU serialized)
// LDS pipe fed, so the spill removal should dominate.
__launch_bounds__(512, 1)
__global__ void sketch_kernel(const float* __restrict__ x, float* __restrict__ outbuf,
                              int staged, int xcoal) {
    __shared__ __align__(16) float2 buf[D_OUTD];
    const int n0 = 2 * blockIdx.x;
    const int n1 = n0 + 1;
    const int t = threadIdx.x;
    const int e = t & 1;
    const int s = t & 31;
    const int kA = ((t >> 5) & 15) << 1;
    const int tA = t ^ kA;                 // phi(t + 512j) = tA + 512j
    const int bB = 512 * (t >> 5);         // phi(B slot)   = bB + 32j + (s ^ 2j)
    const int kc = (t >> 1) & 15;
    const int pp = 32 * (t >> 1);
    const int pc = pp + e;                 // phi(C slot)   = pc + 2*(j^kc)
    const int qc0 = pp + e;                // TRUE C slot   = qc0 + 2j
    const float sgE = e ? -1.0f : 1.0f;

    float xA0, xA1, xB0, xB1;
    if (xcoal) {
        xA0 = x[n0 * D_IN + t]; xA1 = x[n0 * D_IN + t + 512];
        xB0 = x[n1 * D_IN + t]; xB1 = x[n1 * D_IN + t + 512];
    } else {
        xA0 = x[t * NCOL + n0]; xA1 = x[(t + 512) * NCOL + n0];
        xB0 = x[t * NCOL + n1]; xB1 = x[(t + 512) * NCOL + n1];
    }

    // twiddle seeds: wt = W^t (phase A), bb16 = W^(16s) (phase B),
    // bc = W_32^e (phase C'); everything else from squaring chains + c16.
    const float2 wt   = g_tw[t];
    const float2 ws   = g_tw[s];
    const float2 bb16 = csqr(csqr(csqr(csqr(ws))));
    const float2 bc   = e ? make_float2(0.98078528040323044f, -0.19509032201612825f)
                          : make_float2(1.0f, 0.0f);

    float P0r[16], P0i[16], P1r[16], P1i[16];

    // ================= body A: Z = c2[n0] + i*c2[n1] -> split F2 =================
    {
        float Ar[16], Ai[16];
#pragma unroll
        for (int j = 0; j < 16; ++j) buf[tA + 512 * j] = make_float2(0.0f, 0.0f);
        __syncthreads();
        {
            const int   h0 = g_h[2 * D_IN + t];
            const float w0 = g_w[2 * D_IN + t];
            const int   h1 = g_h[2 * D_IN + t + 512];
            const float w1 = g_w[2 * D_IN + t + 512];
            const int   p0 = h0 ^ (((h0 >> 5) & 15) << 1);
            const int   p1 = h1 ^ (((h1 >> 5) & 15) << 1);
            atomicAdd(&buf[p0].x, w0 * xA0);
            atomicAdd(&buf[p0].y, w0 * xB0);
            atomicAdd(&buf[p1].x, w1 * xA1);
            atomicAdd(&buf[p1].y, w1 * xB1);
        }
        __syncthreads();

        FWD_CORE(Ar, Ai)

        // Hermitian split: F2n0 = (Z+B)/2 -> P0, F2n1 = (Z-B)/(2i) -> P1,
        // B = conj(Z[sigma(q)]), one b64 partner read per j.
#pragma unroll
        for (int j = 0; j < 16; ++j) {
            const int q  = qc0 + 2 * j;
            const int L  = 31 - __clz(q | 1);
            const int sq = (q < 2) ? q : (q ^ ((1 << L) - 1));
            const int ps = sq ^ (((sq >> 5) & 15) << 1);
            const float2 pv = buf[ps];
            const float pbr =  pv.x;
            const float pbi = -pv.y;
            P0r[j] =  0.5f * (Ar[j] + pbr);
            P0i[j] =  0.5f * (Ai[j] + pbi);
            P1r[j] =  0.5f * (Ai[j] - pbi);
            P1i[j] = -0.5f * (Ar[j] - pbr);
        }
        __syncthreads();
    }

    // ================= body B: Z = c0[n0] + i*c1[n0]; P0 *= G0 =================
    {
        float Ar[16], Ai[16];
#pragma unroll
        for (int j = 0; j < 16; ++j) buf[tA + 512 * j] = make_float2(0.0f, 0.0f);
        __syncthreads();
        {
            const int   h0 = g_h[t];              const float w0 = g_w[t];
            const int   h1 = g_h[t + 512];        const float w1 = g_w[t + 512];
            const int   h2 = g_h[D_IN + t];       const float w2 = g_w[D_IN + t];
            const int   h3 = g_h[D_IN + t + 512]; const float w3 = g_w[D_IN + t + 512];
            const int   p0 = h0 ^ (((h0 >> 5) & 15) << 1);
            const int   p1 = h1 ^ (((h1 >> 5) & 15) << 1);
            const int   p2 = h2 ^ (((h2 >> 5) & 15) << 1);
            const int   p3 = h3 ^ (((h3 >> 5) & 15) << 1);
            atomicAdd(&buf[p0].x, w0 * xA0);
            atomicAdd(&buf[p1].x, w1 * xA1);
            atomicAdd(&buf[p2].y, w2 * xA0);
            atomicAdd(&buf[p3].y, w3 * xA1);
        }
        __syncthreads();

        FWD_CORE(Ar, Ai)

#pragma unroll
        for (int j = 0; j < 16; ++j) {
            const int q  = qc0 + 2 * j;
            const int L  = 31 - __clz(q | 1);
            const int sq = (q < 2) ? q : (q ^ ((1 << L) - 1));
            const int ps = sq ^ (((sq >> 5) & 15) << 1);
            const float2 pv = buf[ps];
            const float pbr =  pv.x;
            const float pbi = -pv.y;
            const float a2r = Ar[j] * Ar[j] - Ai[j] * Ai[j];
            const float a2i = 2.0f * Ar[j] * Ai[j];
            const float b2r = pbr * pbr - pbi * pbi;
            const float b2i = 2.0f * pbr * pbi;
            const float gr =  0.25f * (a2i - b2i);   // G = -i*(A^2 - B^2)/4
            const float gi = -0.25f * (a2r - b2r);
            const float fr = P0r[j], fi = P0i[j];
            P0r[j] = gr * fr - gi * fi;
            P0i[j] = gr * fi + gi * fr;
        }
        __syncthreads();
    }

    // ================= body C: Z = c0[n1] + i*c1[n1]; P1 *= G1 =================
    {
        float Ar[16], Ai[16];
#pragma unroll
        for (int j = 0; j < 16; ++j) buf[tA + 512 * j] = make_float2(0.0f, 0.0f);
        __syncthreads();
        {
            const int   h0 = g_h[t];              const float w0 = g_w[t];
            const int   h1 = g_h[t + 512];        const float w1 = g_w[t + 512];
            const int   h2 = g_h[D_IN + t];       const float w2 = g_w[D_IN + t];
            const int   h3 = g_h[D_IN + t + 512]; const float w3 = g_w[D_IN + t + 512];
            const int   p0 = h0 ^ (((h0 >> 5) & 15) << 1);
            const int   p1 = h1 ^ (((h1 >> 5) & 15) << 1);
            const int   p2 = h2 ^ (((h2 >> 5) & 15) << 1);
            const int   p3 = h3 ^ (((h3 >> 5) & 15) << 1);
            atomicAdd(&buf[p0].x, w0 * xB0);
            atomicAdd(&buf[p1].x, w1 * xB1);
            atomicAdd(&buf[p2].y, w2 * xB0);
            atomicAdd(&buf[p3].y, w3 * xB1);
        }
        __syncthreads();

        FWD_CORE(Ar, Ai)

#pragma unroll
        for (int j = 0; j < 16; ++j) {
            const int q  = qc0 + 2 * j;
            const int L  = 31 - __clz(q | 1);
            const int sq = (q < 2) ? q : (q ^ ((1 << L) - 1));
            const int ps = sq ^ (((sq >> 5) & 15) << 1);
            const float2 pv = buf[ps];
            const float pbr =  pv.x;
            const float pbi = -pv.y;
            const float a2r = Ar[j] * Ar[j] - Ai[j] * Ai[j];
            const float a2i = 2.0f * Ar[j] * Ai[j];
            const float b2r = pbr * pbr - pbi * pbi;
            const float b2i = 2.0f * pbr * pbi;
            const float gr =  0.25f * (a2i - b2i);
            const float gi = -0.25f * (a2r - b2r);
            const float fr = P1r[j], fi = P1i[j];
            P1r[j] = gr * fr - gi * fi;
            P1i[j] = gr * fi + gi * fr;
        }
        __syncthreads();
    }

    // ===== pack Q = P0 + i*P1, one inverse for both columns =====================
    float Qr[16], Qi[16];
#pragma unroll
    for (int j = 0; j < 16; ++j) {
        Qr[j] = P0r[j] - P1i[j];
        Qi[j] = P0i[j] + P1r[j];
    }

    // stride-1 inverse stage (twiddle-free): pairs are lanes (t, t^1)
#pragma unroll
    for (int j = 0; j < 16; ++j) {
        const float orr = __shfl_xor(Qr[j], 1, 64);
        const float oii = __shfl_xor(Qi[j], 1, 64);
        Qr[j] = orr + sgE * Qr[j];
        Qi[j] = oii + sgE * Qi[j];
    }

    // C'-inv: strides 2..16
    {
        const float2 bc2 = csqr(bc), bc4 = csqr(bc2), bc8 = csqr(bc4);
        REG_PHASE_INV(Qr, Qi, bc8, bc4, bc2, bc)
    }

    // ex2-inv: C layout -> B layout
#pragma unroll
    for (int j = 0; j < 16; ++j) buf[pc + 2 * (j ^ kc)] = make_float2(Qr[j], Qi[j]);
    __syncthreads();
#pragma unroll
    for (int j = 0; j < 16; ++j) { float2 v_ = buf[bB + 32 * j + (s ^ (j << 1))]; Qr[j] = v_.x; Qi[j] = v_.y; }

    // B-inv: strides 32..256
    {
        const float2 bb32 = csqr(bb16), bb64 = csqr(bb32), bb128 = csqr(bb64);
        REG_PHASE_INV(Qr, Qi, bb128, bb64, bb32, bb16)
    }

    // ex1-inv: B layout -> A layout
#pragma unroll
    for (int j = 0; j < 16; ++j) buf[bB + 32 * j + (s ^ (j << 1))] = make_float2(Qr[j], Qi[j]);
    __syncthreads();
#pragma unroll
    for (int j = 0; j < 16; ++j) { float2 v_ = buf[tA + 512 * j]; Qr[j] = v_.x; Qi[j] = v_.y; }

    // A-inv: strides 512..4096
    {
        const float2 wa2 = csqr(wt), wa4 = csqr(wa2), wa8 = csqr(wa4);
        REG_PHASE_INV(Qr, Qi, wa8, wa4, wa2, wt)
    }

    const float scale = 1.0f / (float)D_OUTD;
    if (staged) {
#pragma unroll
        for (int j = 0; j < 16; ++j) {
            outbuf[n0 * D_OUTD + t + 512 * j] = Qr[j] * scale;   // Re -> column n0
            outbuf[n1 * D_OUTD + t + 512 * j] = Qi[j] * scale;   // Im -> column n1
        }
    } else {
#pragma unroll
        for (int j = 0; j < 16; ++j) {
            outbuf[(t + 512 * j) * NCOL + n0] = Qr[j] * scale;
            outbuf[(t + 512 * j) * NCOL + n1] = Qi[j] * scale;
        }
    }
}

// [N][D_out] -> [D_out][N], 32x32 tiles
__global__ void transpose_kernel(const float* __restrict__ in, float* __restrict__ out) {
    __shared__ float tile[32][33];
    int d0 = blockIdx.x * 32;
    int n0 = blockIdx.y * 32;
    int tx = threadIdx.x;
    int ty = threadIdx.y;
#pragma unroll
    for (int j = 0; j < 32; j += 8)
        tile[ty + j][tx] = in[(n0 + ty + j) * D_OUTD + d0 + tx];
    __syncthreads();
#pragma unroll
    for (int j = 0; j < 32; j += 8)
        out[(d0 + ty + j) * NCOL + n0 + tx] = tile[tx][ty + j];
}

extern "C" void kernel_launch(void* const* d_in, const int* in_sizes, int n_in,
                              void* d_out, int out_size, void* d_ws, size_t ws_size,
                              hipStream_t stream) {
    (void)in_sizes; (void)n_in; (void)out_size;
    const float* x     = (const float*)d_in[0];
    const float* hmaps = (const float*)d_in[1];
    float* out = (float*)d_out;

    tw_kernel<<<(D_OUTD / 2 + 255) / 256, 256, 0, stream>>>();
    extract_kernel<<<(ORDER * D_OUTD * D_IN + 255) / 256, 256, 0, stream>>>(hmaps);

    const size_t stage_bytes = (size_t)NCOL * D_OUTD * sizeof(float);
    const size_t xt_bytes    = (size_t)NCOL * D_IN * sizeof(float);

    const float* xs = x;
    int xcoal = 0;
    if (ws_size >= stage_bytes + xt_bytes) {
        float* xT = (float*)((char*)d_ws + stage_bytes);
        xt_kernel<<<dim3(D_IN / 32, NCOL / 32), dim3(32, 8), 0, stream>>>(x, xT);
        xs = xT;
        xcoal = 1;
    }

    if (ws_size >= stage_bytes) {
        float* stag = (float*)d_ws;
        sketch_kernel<<<NCOL / 2, 512, 0, stream>>>(xs, stag, 1, xcoal);
        transpose_kernel<<<dim3(D_OUTD / 32, NCOL / 32), dim3(32, 8), 0, stream>>>(stag, out);
    } else {
        sketch_kernel<<<NCOL / 2, 512, 0, stream>>>(xs, out, 0, xcoal);
    }
}